// Round 3
// baseline (91.400 us; speedup 1.0000x reference)
//
#include <hip/hip_runtime.h>

// Capsule routing on MI355X.
// Identity: softmax over the capsule axis followed by a sum over that axis is
// identically 1 -> the dynamic-routing loop is dead code and
//   out[b, o] = sum_i ( sum_t x[b,t,i] ) * W[i, o]
// => column-sum over T (streams x once, 256 MB, HBM-bound) + tiny matmul.
//
//   K1 colsum_partial : x (32,2048,1024) -> part[64][32][1024]   ~42 us (HBM)
//   K2 chunk_reduce   : part -> xs (32,1024), 128 blocks          ~2 us
//   K3 matmul_small   : xs @ W -> out (32,2048), BG=8             ~4 us

#define BATCH   32
#define TLEN    2048
#define DIN     1024
#define DOUT    2048            // NUM_CAPSULE * DIM_CAPSULE
#define NCHUNK  64
#define RPC     (TLEN / NCHUNK) // 32 rows per chunk

// ---------------------------------------------------------------------------
// K1: partial column sums of x over T.
// grid = (NCHUNK, BATCH) = 2048 blocks, 256 threads -> 32 waves/CU (max occ).
// Thread tx owns float4 column tx; each block streams 32 rows (128 KB).
// ---------------------------------------------------------------------------
__global__ __launch_bounds__(256) void colsum_partial(
    const float* __restrict__ x, float* __restrict__ part)
{
    const int chunk = blockIdx.x;
    const int b     = blockIdx.y;
    const int tx    = threadIdx.x;

    const float4* base = reinterpret_cast<const float4*>(
        x + (size_t)b * TLEN * DIN + (size_t)chunk * RPC * DIN) + tx;

    float4 a0 = make_float4(0.f, 0.f, 0.f, 0.f);
    float4 a1 = make_float4(0.f, 0.f, 0.f, 0.f);
#pragma unroll 8
    for (int r = 0; r < RPC; r += 2) {
        float4 v0 = base[(size_t)r       * (DIN / 4)];
        float4 v1 = base[(size_t)(r + 1) * (DIN / 4)];
        a0.x += v0.x; a0.y += v0.y; a0.z += v0.z; a0.w += v0.w;
        a1.x += v1.x; a1.y += v1.y; a1.z += v1.z; a1.w += v1.w;
    }
    a0.x += a1.x; a0.y += a1.y; a0.z += a1.z; a0.w += a1.w;

    reinterpret_cast<float4*>(part + ((size_t)chunk * BATCH + b) * DIN)[tx] = a0;
}

// ---------------------------------------------------------------------------
// K2: reduce NCHUNK partials -> xs[b][i].
// grid = (DIN/256 = 4 segs, BATCH) = 128 blocks, 256 threads.
// Thread tx owns i = seg*256+tx; loops 64 chunks, 1 KB/wave coalesced loads.
// ---------------------------------------------------------------------------
__global__ __launch_bounds__(256) void chunk_reduce(
    const float* __restrict__ part, float* __restrict__ xs)
{
    const int seg = blockIdx.x;
    const int b   = blockIdx.y;
    const int i   = seg * 256 + threadIdx.x;

    float acc = 0.f;
#pragma unroll 8
    for (int c = 0; c < NCHUNK; ++c)
        acc += part[((size_t)c * BATCH + b) * DIN + i];
    xs[(size_t)b * DIN + i] = acc;
}

// ---------------------------------------------------------------------------
// K3: out[b, o] = sum_i xs[b][i] * W[i, o]
// grid = (DOUT/CB = 16, BATCH/BG = 4) = 64 blocks, 1024 threads (16 waves/CU,
// 4/SIMD). Thread (ol = tx&127, iq = tx>>7) accumulates col o = cb*128+ol over
// i in [iq*128, iq*128+128) for BG=8 batches -> 8 FMA per W dword load.
// xs reads are wave-uniform scalar loads. 8-way partial reduce via 32 KB LDS.
// ---------------------------------------------------------------------------
#define CB 128  // output cols per block
#define BG 8    // batches per block
#define IQ 8    // i-segments per block

__global__ __launch_bounds__(1024) void matmul_small(
    const float* __restrict__ xs, const float* __restrict__ W,
    float* __restrict__ out)
{
    __shared__ float ps[IQ][BG][CB];  // 32 KB

    const int cb = blockIdx.x;
    const int bg = blockIdx.y;
    const int tx = threadIdx.x;
    const int ol = tx & (CB - 1);
    const int iq = tx >> 7;
    const int o  = cb * CB + ol;
    const int i0 = iq * (DIN / IQ);

    const float* wp = W + (size_t)i0 * DOUT + o;
    const float* xb = xs + (size_t)bg * BG * DIN + i0;

    float acc[BG];
#pragma unroll
    for (int bb = 0; bb < BG; ++bb) acc[bb] = 0.f;

#pragma unroll 8
    for (int k = 0; k < DIN / IQ; ++k) {
        const float w = wp[(size_t)k * DOUT];
#pragma unroll
        for (int bb = 0; bb < BG; ++bb)
            acc[bb] += xb[(size_t)bb * DIN + k] * w;
    }
#pragma unroll
    for (int bb = 0; bb < BG; ++bb) ps[iq][bb][ol] = acc[bb];
    __syncthreads();

    // 1024 threads == BG*CB outputs: thread tx -> (bb = tx>>7, ol2 = tx&127)
    const int ol2 = tx & (CB - 1);
    const int bb  = tx >> 7;
    float s = 0.f;
#pragma unroll
    for (int q = 0; q < IQ; ++q) s += ps[q][bb][ol2];
    out[(size_t)(bg * BG + bb) * DOUT + cb * CB + ol2] = s;
}

extern "C" void kernel_launch(void* const* d_in, const int* in_sizes, int n_in,
                              void* d_out, int out_size, void* d_ws, size_t ws_size,
                              hipStream_t stream)
{
    const float* x = (const float*)d_in[0];   // (32, 2048, 1024) f32
    const float* W = (const float*)d_in[1];   // (1024, 2048) f32
    float* out  = (float*)d_out;              // (32, 32, 64) f32 flat
    float* part = (float*)d_ws;                                // 8 MB
    float* xs   = (float*)d_ws + (size_t)NCHUNK * BATCH * DIN; // 128 KB

    dim3 g1(NCHUNK, BATCH);
    colsum_partial<<<g1, 256, 0, stream>>>(x, part);

    dim3 g2(DIN / 256, BATCH);
    chunk_reduce<<<g2, 256, 0, stream>>>(part, xs);

    dim3 g3(DOUT / CB, BATCH / BG);
    matmul_small<<<g3, 1024, 0, stream>>>(xs, W, out);
}

// Round 4
// 74.630 us; speedup vs baseline: 1.2247x; 1.2247x over previous
//
#include <hip/hip_runtime.h>

// Capsule routing on MI355X.
// Identity: softmax over the capsule axis followed by a sum over that axis is
// identically 1 -> the dynamic-routing loop is dead code and
//   out[b, o] = sum_i ( sum_t x[b,t,i] ) * W[i, o]
// => column-sum over T (streams x once, 256 MB, HBM-bound) + tiny matmul.
//
//   memset out (256 KB)                                           ~1 us
//   K1 colsum_partial : x -> part[64][32][1024]                   ~42 us (HBM)
//   K2 chunk_reduce   : part -> xs (32,1024), 128 blocks          ~2.5 us
//   K3 matmul_small   : xs @ W -> out, 1024 x 1-wave blocks,      ~2.5 us
//                       scalar xs loads, atomicAdd iq-partials

#define BATCH   32
#define TLEN    2048
#define DIN     1024
#define DOUT    2048            // NUM_CAPSULE * DIM_CAPSULE
#define NCHUNK  64
#define RPC     (TLEN / NCHUNK) // 32 rows per chunk

// ---------------------------------------------------------------------------
// K1: partial column sums of x over T.
// grid = (NCHUNK, BATCH) = 2048 blocks, 256 threads -> 32 waves/CU (max occ).
// ---------------------------------------------------------------------------
__global__ __launch_bounds__(256) void colsum_partial(
    const float* __restrict__ x, float* __restrict__ part)
{
    const int chunk = blockIdx.x;
    const int b     = blockIdx.y;
    const int tx    = threadIdx.x;

    const float4* base = reinterpret_cast<const float4*>(
        x + (size_t)b * TLEN * DIN + (size_t)chunk * RPC * DIN) + tx;

    float4 a0 = make_float4(0.f, 0.f, 0.f, 0.f);
    float4 a1 = make_float4(0.f, 0.f, 0.f, 0.f);
#pragma unroll 8
    for (int r = 0; r < RPC; r += 2) {
        float4 v0 = base[(size_t)r       * (DIN / 4)];
        float4 v1 = base[(size_t)(r + 1) * (DIN / 4)];
        a0.x += v0.x; a0.y += v0.y; a0.z += v0.z; a0.w += v0.w;
        a1.x += v1.x; a1.y += v1.y; a1.z += v1.z; a1.w += v1.w;
    }
    a0.x += a1.x; a0.y += a1.y; a0.z += a1.z; a0.w += a1.w;

    reinterpret_cast<float4*>(part + ((size_t)chunk * BATCH + b) * DIN)[tx] = a0;
}

// ---------------------------------------------------------------------------
// K2: reduce NCHUNK partials -> xs[b][i].
// grid = (DIN/256 = 4 segs, BATCH) = 128 blocks, 256 threads.
// ---------------------------------------------------------------------------
__global__ __launch_bounds__(256) void chunk_reduce(
    const float* __restrict__ part, float* __restrict__ xs)
{
    const int seg = blockIdx.x;
    const int b   = blockIdx.y;
    const int i   = seg * 256 + threadIdx.x;

    float acc = 0.f;
#pragma unroll 8
    for (int c = 0; c < NCHUNK; ++c)
        acc += part[((size_t)c * BATCH + b) * DIN + i];
    xs[(size_t)b * DIN + i] = acc;
}

// ---------------------------------------------------------------------------
// K3: out[b, o] += sum_{i in seg} xs[b][i] * W[i, o]
// grid = (32 cb, 8 bg, 4 iq) = 1024 one-wave blocks of 64 threads.
// xs addresses are block-uniform (bb compile-time, bg/iq from blockIdx) ->
// scalar s_load path; inner loop = 1 W vector load + 4 v_fmac per k.
// id%8 == cb%8 -> all blocks sharing a W col-slice land on one XCD (1 MB
// slice L2-hot; total W traffic 64 MB ~ 1.9 us).
// iq-partials combined via atomicAdd into memset-zeroed out.
// ---------------------------------------------------------------------------
#define K3_CB 64               // cols per block (= wave width)
#define K3_BG 4                // batches per block
#define K3_IL (DIN / 4)        // 256 i per block

__global__ __launch_bounds__(64) void matmul_small(
    const float* __restrict__ xs, const float* __restrict__ W,
    float* __restrict__ out)
{
    const int cb = blockIdx.x;   // 0..31
    const int bg = blockIdx.y;   // 0..7
    const int iq = blockIdx.z;   // 0..3
    const int ol = threadIdx.x;  // 0..63
    const int o  = cb * K3_CB + ol;
    const int i0 = iq * K3_IL;

    const float* wp = W + (size_t)i0 * DOUT + o;
    const float* x0 = xs + (size_t)(bg * K3_BG + 0) * DIN + i0;
    const float* x1 = xs + (size_t)(bg * K3_BG + 1) * DIN + i0;
    const float* x2 = xs + (size_t)(bg * K3_BG + 2) * DIN + i0;
    const float* x3 = xs + (size_t)(bg * K3_BG + 3) * DIN + i0;

    float a0 = 0.f, a1 = 0.f, a2 = 0.f, a3 = 0.f;
#pragma unroll 8
    for (int k = 0; k < K3_IL; ++k) {
        const float w = wp[(size_t)k * DOUT];
        a0 += x0[k] * w;
        a1 += x1[k] * w;
        a2 += x2[k] * w;
        a3 += x3[k] * w;
    }
    atomicAdd(&out[(size_t)(bg * K3_BG + 0) * DOUT + o], a0);
    atomicAdd(&out[(size_t)(bg * K3_BG + 1) * DOUT + o], a1);
    atomicAdd(&out[(size_t)(bg * K3_BG + 2) * DOUT + o], a2);
    atomicAdd(&out[(size_t)(bg * K3_BG + 3) * DOUT + o], a3);
}

extern "C" void kernel_launch(void* const* d_in, const int* in_sizes, int n_in,
                              void* d_out, int out_size, void* d_ws, size_t ws_size,
                              hipStream_t stream)
{
    const float* x = (const float*)d_in[0];   // (32, 2048, 1024) f32
    const float* W = (const float*)d_in[1];   // (1024, 2048) f32
    float* out  = (float*)d_out;              // (32, 32, 64) f32 flat
    float* part = (float*)d_ws;                                // 8 MB
    float* xs   = (float*)d_ws + (size_t)NCHUNK * BATCH * DIN; // 128 KB

    // zero the atomic accumulation target (graph-capturable memset node)
    hipMemsetAsync(out, 0, (size_t)BATCH * DOUT * sizeof(float), stream);

    dim3 g1(NCHUNK, BATCH);
    colsum_partial<<<g1, 256, 0, stream>>>(x, part);

    dim3 g2(DIN / 256, BATCH);
    chunk_reduce<<<g2, 256, 0, stream>>>(part, xs);

    dim3 g3(DOUT / K3_CB, BATCH / K3_BG, 4);
    matmul_small<<<g3, 64, 0, stream>>>(xs, W, out);
}